// Round 2
// baseline (4647.028 us; speedup 1.0000x reference)
//
#include <hip/hip_runtime.h>
#include <hip/hip_bf16.h>
#include <cstddef>

using u16 = unsigned short;

// Problem constants
static constexpr int Bc = 2, Tc = 8, Nc = 1792, Dc = 4096;
static constexpr int Hc = 8, DHc = 96, INNERc = 768, NLc = 16, FFc = 8192;
static constexpr int BTc = Bc * Tc;          // 16
static constexpr int ROWS_X = BTc * Nc;      // 28672
static constexpr int ROWS_L = BTc * NLc;     // 256
static constexpr float EPSc = 1e-5f;
static constexpr float SCALEc = 0.10206207261596577f;  // 96^-0.5
static constexpr float FMINc = -3.402823466e38f;

__device__ __forceinline__ float bf2f(u16 u) { return __uint_as_float(((unsigned)u) << 16); }
__device__ __forceinline__ u16 f2bf(float f) {
    unsigned i = __float_as_uint(f);
    unsigned r = (i + 0x7fffu + ((i >> 16) & 1u)) >> 16;
    return (u16)r;
}
__device__ __forceinline__ unsigned pk2bf(float a, float b) {
    __hip_bfloat162 p = __float22bfloat162_rn(make_float2(a, b));
    return *(unsigned*)&p;  // a in low 16, b in high 16
}

typedef __bf16 bf16x8 __attribute__((ext_vector_type(8)));
typedef float f32x4 __attribute__((ext_vector_type(4)));

// ---- block reductions (256 threads = 4 waves) ----
__device__ __forceinline__ float block_sum(float v, float* red) {
    for (int o = 32; o > 0; o >>= 1) v += __shfl_down(v, o, 64);
    int lane = threadIdx.x & 63, w = threadIdx.x >> 6;
    if (lane == 0) red[w] = v;
    __syncthreads();
    float r = red[0] + red[1] + red[2] + red[3];
    __syncthreads();
    return r;
}
__device__ __forceinline__ float block_max(float v, float* red) {
    for (int o = 32; o > 0; o >>= 1) v = fmaxf(v, __shfl_down(v, o, 64));
    int lane = threadIdx.x & 63, w = threadIdx.x >> 6;
    if (lane == 0) red[w] = v;
    __syncthreads();
    float r = fmaxf(fmaxf(red[0], red[1]), fmaxf(red[2], red[3]));
    __syncthreads();
    return r;
}

// ---- per-row LN stats for x (fp32): mu, rsigma ----
__global__ __launch_bounds__(256) void row_stats_k(const float* __restrict__ x,
                                                   float* __restrict__ mu, float* __restrict__ rs) {
    __shared__ float red[4];
    int r = blockIdx.x;
    const float* row = x + (size_t)r * Dc;
    float s = 0.f, s2 = 0.f;
#pragma unroll
    for (int it = 0; it < 4; ++it) {
        float4 f = *(const float4*)(row + (threadIdx.x + it * 256) * 4);
        s += f.x + f.y + f.z + f.w;
        s2 += f.x * f.x + f.y * f.y + f.z * f.z + f.w * f.w;
    }
    s = block_sum(s, red);
    s2 = block_sum(s2, red);
    if (threadIdx.x == 0) {
        float m = s * (1.f / Dc);
        float v = s2 * (1.f / Dc) - m * m;
        mu[r] = m;
        rs[r] = rsqrtf(v + EPSc);
    }
}

// ---- u[c]=sum_k g[k]W[k][c], t[c]=sum_k b[k]W[k][c]  (LN fold vectors, fp32) ----
__global__ __launch_bounds__(256) void colsums_k(const float* __restrict__ W, const float* __restrict__ g,
                                                 const float* __restrict__ b, float* __restrict__ u,
                                                 float* __restrict__ t, int K, int NN) {
    int c = blockIdx.x * 256 + threadIdx.x;
    float su = 0.f, st = 0.f;
    for (int k = 0; k < K; k++) {
        float w = W[(size_t)k * NN + c];
        su += g[k] * w;
        st += b[k] * w;
    }
    u[c] = su;
    t[c] = st;
}

// ---- fp32 -> bf16 transpose (optionally scaling input row r by g[r]) ----
template <bool SC>
__global__ __launch_bounds__(256) void transpose_k(const float* __restrict__ in, u16* __restrict__ out,
                                                   int R, int C, const float* __restrict__ g) {
    __shared__ u16 t[32][33];
    int c0 = blockIdx.x * 32, r0 = blockIdx.y * 32;
    int lx = threadIdx.x & 31, ly = threadIdx.x >> 5;
#pragma unroll
    for (int i = 0; i < 32; i += 8) {
        float val = in[(size_t)(r0 + ly + i) * C + c0 + lx];
        if (SC) val *= g[r0 + ly + i];
        t[ly + i][lx] = f2bf(val);
    }
    __syncthreads();
#pragma unroll
    for (int i = 0; i < 32; i += 8)
        out[(size_t)(c0 + ly + i) * R + r0 + lx] = t[lx][ly + i];
}

// ---- q = SCALE * LN(latents) @ wq   (16 x 768, all fp32) ----
__global__ __launch_bounds__(256) void qproj_k(const float* __restrict__ lat, const float* __restrict__ g,
                                               const float* __restrict__ b, const float* __restrict__ wq,
                                               float* __restrict__ q) {
    __shared__ float qs[Dc];
    __shared__ float red[4];
    int i = blockIdx.x, ch = blockIdx.y;
    const float* row = lat + (size_t)i * Dc;
    float4 fv[4];
    float s = 0.f, s2 = 0.f;
#pragma unroll
    for (int it = 0; it < 4; ++it) {
        fv[it] = *(const float4*)(row + (threadIdx.x + it * 256) * 4);
        s += fv[it].x + fv[it].y + fv[it].z + fv[it].w;
        s2 += fv[it].x * fv[it].x + fv[it].y * fv[it].y + fv[it].z * fv[it].z + fv[it].w * fv[it].w;
    }
    s = block_sum(s, red);
    s2 = block_sum(s2, red);
    float m = s * (1.f / Dc), rr = rsqrtf(s2 * (1.f / Dc) - m * m + EPSc);
#pragma unroll
    for (int it = 0; it < 4; ++it) {
        int base = (threadIdx.x + it * 256) * 4;
        float4 gg = *(const float4*)(g + base);
        float4 bb = *(const float4*)(b + base);
        float xs[4] = {fv[it].x, fv[it].y, fv[it].z, fv[it].w};
        float gs[4] = {gg.x, gg.y, gg.z, gg.w};
        float bs[4] = {bb.x, bb.y, bb.z, bb.w};
#pragma unroll
        for (int e = 0; e < 4; e++) qs[base + e] = (xs[e] - m) * rr * gs[e] + bs[e];
    }
    __syncthreads();
    int c = ch * 256 + threadIdx.x;
    float acc = 0.f;
    for (int k = 0; k < Dc; k += 4) {
        acc += qs[k] * wq[(size_t)k * INNERc + c];
        acc += qs[k + 1] * wq[(size_t)(k + 1) * INNERc + c];
        acc += qs[k + 2] * wq[(size_t)(k + 2) * INNERc + c];
        acc += qs[k + 3] * wq[(size_t)(k + 3) * INNERc + c];
    }
    q[i * INNERc + c] = acc * SCALEc;
}

// ---- 128x128 MFMA GEMM, BK=32, 4 waves, 16x16x32 bf16 ----
// EPI: 1 = +latents(fp32) residual -> fp32 ; 2 = gelu -> bf16 ; 3 = +resf -> fp32 ;
//      4 = LN-fold epilogue rs*(acc - mu*u) + t -> bf16
// BKXN: B given fp32 (K,N) row-major (convert+transpose on stage); else B bf16 (N,K).
// AF32: A is fp32 (convert on stage); else A bf16.
template <int EPI, bool BKXN, bool AF32>
__global__ __launch_bounds__(256) void gemm_k(
    const void* __restrict__ Av, const void* __restrict__ Bv,
    u16* __restrict__ Cb, float* __restrict__ Cf,
    int M, int N, int K,
    const float* __restrict__ mu, const float* __restrict__ rs,
    const float* __restrict__ uvec, const float* __restrict__ tvec,
    const float* __restrict__ resf) {
    __shared__ __align__(16) u16 As[128 * 32];
    __shared__ __align__(16) u16 Bs[128 * 32];
    int tid = threadIdx.x;
    unsigned l = blockIdx.y * gridDim.x + blockIdx.x;
    unsigned G = gridDim.x * gridDim.y;
    unsigned wl = (l & 7u) * (G >> 3) + (l >> 3);   // XCD-contiguous work list
    int nt = wl % gridDim.x, mt = wl / gridDim.x;
    int m0 = mt * 128, n0 = nt * 128;
    int lane = tid & 63, wave = tid >> 6;
    int wm = (wave & 1) << 6, wn = (wave >> 1) << 6;
    int lm = lane & 15, quad = lane >> 4;
    int ko = quad * 8;

    const float* Af = (const float*)Av;
    const u16* Ab = (const u16*)Av;
    const float* Bf = (const float*)Bv;
    const u16* Bb = (const u16*)Bv;

    f32x4 acc[4][4];
#pragma unroll
    for (int mi = 0; mi < 4; mi++)
#pragma unroll
        for (int ni = 0; ni < 4; ni++) acc[mi][ni] = f32x4{0.f, 0.f, 0.f, 0.f};

    for (int k0 = 0; k0 < K; k0 += 32) {
        if (AF32) {
#pragma unroll
            for (int it = 0; it < 4; ++it) {
                int cid = tid + (it << 8);
                int row = cid >> 3, qq = cid & 7;
                float4 f = *(const float4*)(Af + (size_t)(m0 + row) * K + k0 + qq * 4);
                uint2 pk;
                pk.x = pk2bf(f.x, f.y);
                pk.y = pk2bf(f.z, f.w);
                *(uint2*)&As[row * 32 + qq * 4] = pk;
            }
        } else {
#pragma unroll
            for (int it = 0; it < 2; ++it) {
                int cid = tid + (it << 8);
                int row = cid >> 2, cc = cid & 3;
                *(uint4*)&As[row * 32 + cc * 8] = *(const uint4*)(Ab + (size_t)(m0 + row) * K + k0 + cc * 8);
            }
        }
        if (!BKXN) {
#pragma unroll
            for (int it = 0; it < 2; ++it) {
                int cid = tid + (it << 8);
                int row = cid >> 2, cc = cid & 3;
                *(uint4*)&Bs[row * 32 + cc * 8] = *(const uint4*)(Bb + (size_t)(n0 + row) * K + k0 + cc * 8);
            }
        } else {
#pragma unroll
            for (int it = 0; it < 4; ++it) {
                int cid = tid + (it << 8);           // 0..1023
                int kk = cid >> 5, nc = cid & 31;    // kk 0..31, nc 0..31
                float4 f = *(const float4*)(Bf + (size_t)(k0 + kk) * N + n0 + nc * 4);
                Bs[(nc * 4 + 0) * 32 + kk] = f2bf(f.x);
                Bs[(nc * 4 + 1) * 32 + kk] = f2bf(f.y);
                Bs[(nc * 4 + 2) * 32 + kk] = f2bf(f.z);
                Bs[(nc * 4 + 3) * 32 + kk] = f2bf(f.w);
            }
        }
        __syncthreads();
        bf16x8 af[4], bq[4];
#pragma unroll
        for (int mi = 0; mi < 4; mi++) af[mi] = *(const bf16x8*)&As[(wm + mi * 16 + lm) * 32 + ko];
#pragma unroll
        for (int ni = 0; ni < 4; ni++) bq[ni] = *(const bf16x8*)&Bs[(wn + ni * 16 + lm) * 32 + ko];
#pragma unroll
        for (int mi = 0; mi < 4; mi++)
#pragma unroll
            for (int ni = 0; ni < 4; ni++)
                acc[mi][ni] = __builtin_amdgcn_mfma_f32_16x16x32_bf16(af[mi], bq[ni], acc[mi][ni], 0, 0, 0);
        __syncthreads();
    }
#pragma unroll
    for (int mi = 0; mi < 4; mi++) {
#pragma unroll
        for (int r = 0; r < 4; r++) {
            int row = m0 + wm + mi * 16 + quad * 4 + r;
#pragma unroll
            for (int ni = 0; ni < 4; ni++) {
                int col = n0 + wn + ni * 16 + lm;
                float v = acc[mi][ni][r];
                if constexpr (EPI == 1) {
                    v += resf[(size_t)(row & 15) * Dc + col];   // latents broadcast residual
                    Cf[(size_t)row * N + col] = v;
                } else if constexpr (EPI == 2) {
                    v = 0.5f * v * (1.f + erff(v * 0.70710678118654752f));
                    Cb[(size_t)row * N + col] = f2bf(v);
                } else if constexpr (EPI == 3) {
                    v += resf[(size_t)row * N + col];
                    Cf[(size_t)row * N + col] = v;
                } else {
                    v = rs[row] * (v - mu[row] * uvec[col]) + tvec[col];
                    Cb[(size_t)row * N + col] = f2bf(v);
                }
            }
        }
    }
}

// ---- sim[bth][i][j] = q . k  (q fp32, k bf16) ----
__global__ __launch_bounds__(256) void sim_qk_k(const float* __restrict__ q, const u16* __restrict__ kv,
                                                float* __restrict__ sim) {
    __shared__ float qs[16 * 96];
    __shared__ __align__(16) u16 ks[256 * 96];
    int bth = blockIdx.x, bt = bth >> 3, h = bth & 7;
    int j0 = blockIdx.y * 256;
    for (int idx = threadIdx.x; idx < 1536; idx += 256) {
        int i = idx / 96, d = idx - i * 96;
        qs[idx] = q[i * INNERc + h * DHc + d];
    }
#pragma unroll
    for (int it = 0; it < 12; ++it) {
        int cid = threadIdx.x + it * 256;
        int row = cid / 12, c = cid - row * 12;
        *(uint4*)&ks[row * 96 + c * 8] =
            *(const uint4*)(kv + (size_t)(bt * Nc + j0 + row) * 1536 + h * DHc + c * 8);
    }
    __syncthreads();
    float acc[16];
#pragma unroll
    for (int i = 0; i < 16; i++) acc[i] = 0.f;
    int j = threadIdx.x;
#pragma unroll
    for (int c = 0; c < 12; c++) {
        uint4 raw = *(const uint4*)&ks[j * 96 + c * 8];
        const u16* pe = (const u16*)&raw;
        float kf[8];
#pragma unroll
        for (int e = 0; e < 8; e++) kf[e] = bf2f(pe[e]);
#pragma unroll
        for (int i = 0; i < 16; i++) {
            float a = 0.f;
#pragma unroll
            for (int e = 0; e < 8; e++) a += qs[i * 96 + c * 8 + e] * kf[e];
            acc[i] += a;
        }
    }
#pragma unroll
    for (int i = 0; i < 16; i++)
        sim[((size_t)bth * 16 + i) * Nc + j0 + j] = acc[i];
}

// ---- softmax row transform, exactly in reference order ----
__global__ __launch_bounds__(256) void softmax_k(float* __restrict__ sim, const int* __restrict__ mask,
                                                 const float* __restrict__ guid) {
    __shared__ float red[4];
    int r = blockIdx.x;      // bt*128 + h*16 + i
    int bt = r >> 7;
    float* row = sim + (size_t)r * Nc;
    const int* mrow = mask + bt * Nc;
    const float* grow = guid + bt * Nc;
    float v[7];
    float mx = FMINc;
#pragma unroll
    for (int e = 0; e < 7; e++) { v[e] = row[threadIdx.x + e * 256]; mx = fmaxf(mx, v[e]); }
    float max1 = block_max(mx, red);
    float mx2 = FMINc;
#pragma unroll
    for (int e = 0; e < 7; e++) {
        int j = threadIdx.x + e * 256;
        float s = v[e] - max1;
        if (mrow[j] != 0) s = FMINc;
        s *= grow[j];
        v[e] = s;
        mx2 = fmaxf(mx2, s);
    }
    float max2 = block_max(mx2, red);
    float sum = 0.f;
#pragma unroll
    for (int e = 0; e < 7; e++) { v[e] = expf(v[e] - max2); sum += v[e]; }
    float tot = block_sum(sum, red);
    float inv = 1.f / tot;
#pragma unroll
    for (int e = 0; e < 7; e++) row[threadIdx.x + e * 256] = v[e] * inv;
}

// ---- out[bt*16+i, h*96+d] = sum_j p[i][j] v[j][d] -> bf16 ----
__global__ __launch_bounds__(256) void attn_out_k(const float* __restrict__ sim, const u16* __restrict__ kv,
                                                  u16* __restrict__ aout) {
    __shared__ __align__(16) u16 vs[128 * 96];
    __shared__ float ps[16 * 128];
    int bth = blockIdx.x, bt = bth >> 3, h = bth & 7;
    float acc[6];
    int ie[6], de[6];
#pragma unroll
    for (int e = 0; e < 6; e++) {
        int el = threadIdx.x + e * 256;
        ie[e] = el / 96;
        de[e] = el - ie[e] * 96;
        acc[e] = 0.f;
    }
    for (int jt = 0; jt < 14; ++jt) {
        int j0 = jt * 128;
#pragma unroll
        for (int it = 0; it < 6; ++it) {
            int cid = threadIdx.x + it * 256;  // 0..1535
            int row = cid / 12, c = cid - row * 12;
            *(uint4*)&vs[row * 96 + c * 8] =
                *(const uint4*)(kv + (size_t)(bt * Nc + j0 + row) * 1536 + INNERc + h * DHc + c * 8);
        }
#pragma unroll
        for (int it = 0; it < 8; ++it) {
            int cid = threadIdx.x + it * 256;
            int ii = cid >> 7, jj = cid & 127;
            ps[ii * 128 + jj] = sim[((size_t)bth * 16 + ii) * Nc + j0 + jj];
        }
        __syncthreads();
        for (int jj = 0; jj < 128; ++jj) {
#pragma unroll
            for (int e = 0; e < 6; e++)
                acc[e] += ps[ie[e] * 128 + jj] * bf2f(vs[jj * 96 + de[e]]);
        }
        __syncthreads();
    }
#pragma unroll
    for (int e = 0; e < 6; e++)
        aout[(size_t)(bt * 16 + ie[e]) * INNERc + h * DHc + de[e]] = f2bf(acc[e]);
}

// ---- LayerNorm over fp32 rows -> bf16 (OUTF32=false) or fp32 (true) ----
template <bool OUTF32>
__global__ __launch_bounds__(256) void ln_rows_k(const float* __restrict__ in, const float* __restrict__ g,
                                                 const float* __restrict__ b, void* __restrict__ outv) {
    __shared__ float red[4];
    int r = blockIdx.x;
    const float* row = in + (size_t)r * Dc;
    float4 v[4];
    float s = 0.f, s2 = 0.f;
#pragma unroll
    for (int it = 0; it < 4; ++it) {
        v[it] = *(const float4*)(row + (threadIdx.x + it * 256) * 4);
        s += v[it].x + v[it].y + v[it].z + v[it].w;
        s2 += v[it].x * v[it].x + v[it].y * v[it].y + v[it].z * v[it].z + v[it].w * v[it].w;
    }
    s = block_sum(s, red);
    s2 = block_sum(s2, red);
    float m = s * (1.f / Dc), rr = rsqrtf(s2 * (1.f / Dc) - m * m + EPSc);
#pragma unroll
    for (int it = 0; it < 4; ++it) {
        int base = (threadIdx.x + it * 256) * 4;
        float4 gg = *(const float4*)(g + base);
        float4 bb = *(const float4*)(b + base);
        float xs[4] = {v[it].x, v[it].y, v[it].z, v[it].w};
        float gs[4] = {gg.x, gg.y, gg.z, gg.w};
        float bs[4] = {bb.x, bb.y, bb.z, bb.w};
        float o[4];
#pragma unroll
        for (int e = 0; e < 4; e++) o[e] = (xs[e] - m) * rr * gs[e] + bs[e];
        if (OUTF32) {
            *(float4*)((float*)outv + (size_t)r * Dc + base) = make_float4(o[0], o[1], o[2], o[3]);
        } else {
            u16 tmp[4];
#pragma unroll
            for (int e = 0; e < 4; e++) tmp[e] = f2bf(o[e]);
            *(uint2*)((u16*)outv + (size_t)r * Dc + base) = *(uint2*)tmp;
        }
    }
}

extern "C" void kernel_launch(void* const* d_in, const int* in_sizes, int n_in,
                              void* d_out, int out_size, void* d_ws, size_t ws_size,
                              hipStream_t stream) {
    const float* x    = (const float*)d_in[0];
    const float* guid = (const float*)d_in[1];
    const int*   mask = (const int*)d_in[2];
    const float* lat  = (const float*)d_in[3];
    const float* nm_g = (const float*)d_in[4];
    const float* nm_b = (const float*)d_in[5];
    const float* nl_g = (const float*)d_in[6];
    const float* nl_b = (const float*)d_in[7];
    const float* wq   = (const float*)d_in[8];
    const float* wkv  = (const float*)d_in[9];
    const float* wout = (const float*)d_in[10];
    const float* ff_g = (const float*)d_in[11];
    const float* ff_b = (const float*)d_in[12];
    const float* w1   = (const float*)d_in[13];
    const float* w2   = (const float*)d_in[14];
    const float* fn_g = (const float*)d_in[15];
    const float* fn_b = (const float*)d_in[16];

    char* base = (char*)d_ws;
    size_t off = 0;
    auto alloc = [&](size_t bytes) -> void* {
        void* r = base + off;
        off = (off + bytes + 255) & ~(size_t)255;
        return r;
    };
    // total ~137 MB of workspace
    u16*   kv    = (u16*)alloc((size_t)ROWS_X * 1536 * 2);   // 88 MB (bf16)
    u16*   wkvT  = (u16*)alloc((size_t)1536 * 4096 * 2);     // 12.6 MB (g-folded bf16)
    u16*   woutT = (u16*)alloc((size_t)4096 * 768 * 2);      // 6.3 MB (bf16)
    float* mu    = (float*)alloc((size_t)ROWS_X * 4);
    float* rs    = (float*)alloc((size_t)ROWS_X * 4);
    float* uvec  = (float*)alloc(1536 * 4);
    float* tvec  = (float*)alloc(1536 * 4);
    float* qb    = (float*)alloc((size_t)NLc * INNERc * 4);
    float* simb  = (float*)alloc((size_t)BTc * Hc * NLc * Nc * 4);  // 14.7 MB
    u16*   aout  = (u16*)alloc((size_t)ROWS_L * INNERc * 2);
    float* lat1  = (float*)alloc((size_t)ROWS_L * Dc * 4);
    u16*   aff   = (u16*)alloc((size_t)ROWS_L * Dc * 2);
    u16*   hb    = (u16*)alloc((size_t)ROWS_L * FFc * 2);
    float* lat2  = (float*)alloc((size_t)ROWS_L * Dc * 4);
    (void)in_sizes; (void)n_in; (void)out_size; (void)ws_size;

    row_stats_k<<<ROWS_X, 256, 0, stream>>>(x, mu, rs);
    colsums_k<<<6, 256, 0, stream>>>(wkv, nm_g, nm_b, uvec, tvec, 4096, 1536);
    transpose_k<true><<<dim3(1536 / 32, 4096 / 32), 256, 0, stream>>>(wkv, wkvT, 4096, 1536, nm_g);
    transpose_k<false><<<dim3(4096 / 32, 768 / 32), 256, 0, stream>>>(wout, woutT, 768, 4096, nullptr);
    qproj_k<<<dim3(16, 3), 256, 0, stream>>>(lat, nl_g, nl_b, wq, qb);

    // KV projection: LN folded into epilogue; A = raw fp32 x, converted on stage
    gemm_k<4, false, true><<<dim3(12, 224), 256, 0, stream>>>(x, wkvT, kv, nullptr, ROWS_X, 1536, 4096,
                                                              mu, rs, uvec, tvec, nullptr);

    sim_qk_k<<<dim3(128, 7), 256, 0, stream>>>(qb, kv, simb);
    softmax_k<<<2048, 256, 0, stream>>>(simb, mask, guid);
    attn_out_k<<<128, 256, 0, stream>>>(simb, kv, aout);

    gemm_k<1, false, false><<<dim3(32, 2), 256, 0, stream>>>(aout, woutT, nullptr, lat1, ROWS_L, 4096, 768,
                                                             nullptr, nullptr, nullptr, nullptr, lat);
    ln_rows_k<false><<<ROWS_L, 256, 0, stream>>>(lat1, ff_g, ff_b, aff);
    gemm_k<2, true, false><<<dim3(64, 2), 256, 0, stream>>>(aff, w1, hb, nullptr, ROWS_L, 8192, 4096,
                                                            nullptr, nullptr, nullptr, nullptr, nullptr);
    gemm_k<3, true, false><<<dim3(32, 2), 256, 0, stream>>>(hb, w2, nullptr, lat2, ROWS_L, 4096, 8192,
                                                            nullptr, nullptr, nullptr, nullptr, lat1);
    ln_rows_k<true><<<ROWS_L, 256, 0, stream>>>(lat2, fn_g, fn_b, d_out);
}

// Round 3
// 2287.120 us; speedup vs baseline: 2.0318x; 2.0318x over previous
//
#include <hip/hip_runtime.h>
#include <hip/hip_bf16.h>
#include <cstddef>

using u16 = unsigned short;

// Problem constants
static constexpr int Bc = 2, Tc = 8, Nc = 1792, Dc = 4096;
static constexpr int Hc = 8, DHc = 96, INNERc = 768, NLc = 16, FFc = 8192;
static constexpr int BTc = Bc * Tc;          // 16
static constexpr int ROWS_X = BTc * Nc;      // 28672
static constexpr int ROWS_L = BTc * NLc;     // 256
static constexpr float EPSc = 1e-5f;
static constexpr float SCALEc = 0.10206207261596577f;  // 96^-0.5
static constexpr float FMINc = -3.402823466e38f;

__device__ __forceinline__ float bf2f(u16 u) { return __uint_as_float(((unsigned)u) << 16); }
__device__ __forceinline__ u16 f2bf(float f) {
    unsigned i = __float_as_uint(f);
    unsigned r = (i + 0x7fffu + ((i >> 16) & 1u)) >> 16;
    return (u16)r;
}
__device__ __forceinline__ unsigned pk2bf(float a, float b) {
    __hip_bfloat162 p = __float22bfloat162_rn(make_float2(a, b));
    return *(unsigned*)&p;
}
// async global->LDS, 16 B per lane; LDS dest = wave-uniform base + lane*16
__device__ __forceinline__ void gld_lds16(const u16* g, u16* l) {
    __builtin_amdgcn_global_load_lds((const __attribute__((address_space(1))) void*)g,
                                     (__attribute__((address_space(3))) void*)l, 16, 0, 0);
}

typedef __bf16 bf16x8 __attribute__((ext_vector_type(8)));
typedef float f32x4 __attribute__((ext_vector_type(4)));

// ---- block reductions (256 threads = 4 waves) ----
__device__ __forceinline__ float block_sum(float v, float* red) {
    for (int o = 32; o > 0; o >>= 1) v += __shfl_down(v, o, 64);
    int lane = threadIdx.x & 63, w = threadIdx.x >> 6;
    if (lane == 0) red[w] = v;
    __syncthreads();
    float r = red[0] + red[1] + red[2] + red[3];
    __syncthreads();
    return r;
}
__device__ __forceinline__ float block_max(float v, float* red) {
    for (int o = 32; o > 0; o >>= 1) v = fmaxf(v, __shfl_down(v, o, 64));
    int lane = threadIdx.x & 63, w = threadIdx.x >> 6;
    if (lane == 0) red[w] = v;
    __syncthreads();
    float r = fmaxf(fmaxf(red[0], red[1]), fmaxf(red[2], red[3]));
    __syncthreads();
    return r;
}

// ---- per-row LN stats for x (fp32): mu, rsigma; optionally emit bf16 copy ----
template <bool CVT>
__global__ __launch_bounds__(256) void row_stats_k(const float* __restrict__ x,
                                                   float* __restrict__ mu, float* __restrict__ rs,
                                                   u16* __restrict__ xb) {
    __shared__ float red[4];
    int r = blockIdx.x;
    const float* row = x + (size_t)r * Dc;
    float s = 0.f, s2 = 0.f;
#pragma unroll
    for (int it = 0; it < 4; ++it) {
        int base = (threadIdx.x + it * 256) * 4;
        float4 f = *(const float4*)(row + base);
        s += f.x + f.y + f.z + f.w;
        s2 += f.x * f.x + f.y * f.y + f.z * f.z + f.w * f.w;
        if (CVT) {
            uint2 pk;
            pk.x = pk2bf(f.x, f.y);
            pk.y = pk2bf(f.z, f.w);
            *(uint2*)&xb[(size_t)r * Dc + base] = pk;
        }
    }
    s = block_sum(s, red);
    s2 = block_sum(s2, red);
    if (threadIdx.x == 0) {
        float m = s * (1.f / Dc);
        float v = s2 * (1.f / Dc) - m * m;
        mu[r] = m;
        rs[r] = rsqrtf(v + EPSc);
    }
}

__global__ __launch_bounds__(256) void zero_k(float* __restrict__ p, int n) {
    int i = blockIdx.x * 256 + threadIdx.x;
    if (i < n) p[i] = 0.f;
}

// ---- u[c]+=sum_k g[k]W[k][c], t[c]+=sum_k b[k]W[k][c] over K-chunk (atomic) ----
__global__ __launch_bounds__(256) void colsums_part_k(const float* __restrict__ W, const float* __restrict__ g,
                                                      const float* __restrict__ b, float* __restrict__ u,
                                                      float* __restrict__ t, int NN) {
    int c = blockIdx.x * 256 + threadIdx.x;
    int k0 = blockIdx.y * 128;
    float su = 0.f, st = 0.f;
    for (int k = k0; k < k0 + 128; k++) {
        float w = W[(size_t)k * NN + c];
        su += g[k] * w;
        st += b[k] * w;
    }
    atomicAdd(&u[c], su);
    atomicAdd(&t[c], st);
}

// ---- fp32 -> bf16 transpose (optionally scaling input row r by g[r]) ----
template <bool SC>
__global__ __launch_bounds__(256) void transpose_k(const float* __restrict__ in, u16* __restrict__ out,
                                                   int R, int C, const float* __restrict__ g) {
    __shared__ u16 t[32][33];
    int c0 = blockIdx.x * 32, r0 = blockIdx.y * 32;
    int lx = threadIdx.x & 31, ly = threadIdx.x >> 5;
#pragma unroll
    for (int i = 0; i < 32; i += 8) {
        float val = in[(size_t)(r0 + ly + i) * C + c0 + lx];
        if (SC) val *= g[r0 + ly + i];
        t[ly + i][lx] = f2bf(val);
    }
    __syncthreads();
#pragma unroll
    for (int i = 0; i < 32; i += 8)
        out[(size_t)(c0 + ly + i) * R + r0 + lx] = t[lx][ly + i];
}

// ---- q = SCALE * LN(latents) @ wq   (16 x 768, all fp32) ----
__global__ __launch_bounds__(256) void qproj_k(const float* __restrict__ lat, const float* __restrict__ g,
                                               const float* __restrict__ b, const float* __restrict__ wq,
                                               float* __restrict__ q) {
    __shared__ float qs[Dc];
    __shared__ float red[4];
    int i = blockIdx.x, ch = blockIdx.y;
    const float* row = lat + (size_t)i * Dc;
    float4 fv[4];
    float s = 0.f, s2 = 0.f;
#pragma unroll
    for (int it = 0; it < 4; ++it) {
        fv[it] = *(const float4*)(row + (threadIdx.x + it * 256) * 4);
        s += fv[it].x + fv[it].y + fv[it].z + fv[it].w;
        s2 += fv[it].x * fv[it].x + fv[it].y * fv[it].y + fv[it].z * fv[it].z + fv[it].w * fv[it].w;
    }
    s = block_sum(s, red);
    s2 = block_sum(s2, red);
    float m = s * (1.f / Dc), rr = rsqrtf(s2 * (1.f / Dc) - m * m + EPSc);
#pragma unroll
    for (int it = 0; it < 4; ++it) {
        int base = (threadIdx.x + it * 256) * 4;
        float4 gg = *(const float4*)(g + base);
        float4 bb = *(const float4*)(b + base);
        float xs[4] = {fv[it].x, fv[it].y, fv[it].z, fv[it].w};
        float gs[4] = {gg.x, gg.y, gg.z, gg.w};
        float bs[4] = {bb.x, bb.y, bb.z, bb.w};
#pragma unroll
        for (int e = 0; e < 4; e++) qs[base + e] = (xs[e] - m) * rr * gs[e] + bs[e];
    }
    __syncthreads();
    int c = ch * 256 + threadIdx.x;
    float acc = 0.f;
    for (int k = 0; k < Dc; k += 4) {
        acc += qs[k] * wq[(size_t)k * INNERc + c];
        acc += qs[k + 1] * wq[(size_t)(k + 1) * INNERc + c];
        acc += qs[k + 2] * wq[(size_t)(k + 2) * INNERc + c];
        acc += qs[k + 3] * wq[(size_t)(k + 3) * INNERc + c];
    }
    q[i * INNERc + c] = acc * SCALEc;
}

// ================= FAST PATH: all-bf16 GEMM with global_load_lds staging =================
// A bf16 (M,K), B bf16 (N,K). 128x128 tile, BK=32, 4 waves, 16x16x32 MFMA.
// EPI: 1 = +latents(fp32,broadcast) -> fp32 ; 2 = gelu -> bf16 ; 3 = +resf -> fp32 ;
//      4 = LN-fold epilogue rs*(acc - mu*u) + t -> bf16
template <int EPI>
__global__ __launch_bounds__(256) void gemm_bf_k(
    const u16* __restrict__ A, const u16* __restrict__ Bm,
    u16* __restrict__ Cb, float* __restrict__ Cf,
    int M, int N, int K,
    const float* __restrict__ mu, const float* __restrict__ rs,
    const float* __restrict__ uvec, const float* __restrict__ tvec,
    const float* __restrict__ resf) {
    __shared__ __align__(16) u16 As[128 * 32];
    __shared__ __align__(16) u16 Bs[128 * 32];
    int tid = threadIdx.x;
    unsigned l = blockIdx.y * gridDim.x + blockIdx.x;
    unsigned G = gridDim.x * gridDim.y;
    unsigned wl = (l & 7u) * (G >> 3) + (l >> 3);   // XCD-contiguous work list
    int nt = wl % gridDim.x, mt = wl / gridDim.x;
    int m0 = mt * 128, n0 = nt * 128;
    int lane = tid & 63, wave = tid >> 6;
    int wm = (wave & 1) << 6, wn = (wave >> 1) << 6;
    int lm = lane & 15, quad = lane >> 4;
    int ko = quad * 8;

    // staging: wave stages rows [wave*32, wave*32+32) of both tiles;
    // lane covers row wave*32 + it*16 + lane/4, 16B chunk (lane&3)*8 elems.
    int srow = wave * 32 + (lane >> 2);
    int sc8 = (lane & 3) * 8;
    const u16* Ap = A + (size_t)(m0 + srow) * K + sc8;
    const u16* Bp = Bm + (size_t)(n0 + srow) * K + sc8;
    u16* AsW = &As[(wave * 32) * 32];
    u16* BsW = &Bs[(wave * 32) * 32];

    f32x4 acc[4][4];
#pragma unroll
    for (int mi = 0; mi < 4; mi++)
#pragma unroll
        for (int ni = 0; ni < 4; ni++) acc[mi][ni] = f32x4{0.f, 0.f, 0.f, 0.f};

    for (int k0 = 0; k0 < K; k0 += 32) {
        gld_lds16(Ap, AsW);
        gld_lds16(Ap + (size_t)16 * K, AsW + 16 * 32);
        gld_lds16(Bp, BsW);
        gld_lds16(Bp + (size_t)16 * K, BsW + 16 * 32);
        Ap += 32;
        Bp += 32;
        __syncthreads();
        bf16x8 af[4], bq[4];
#pragma unroll
        for (int mi = 0; mi < 4; mi++) af[mi] = *(const bf16x8*)&As[(wm + mi * 16 + lm) * 32 + ko];
#pragma unroll
        for (int ni = 0; ni < 4; ni++) bq[ni] = *(const bf16x8*)&Bs[(wn + ni * 16 + lm) * 32 + ko];
#pragma unroll
        for (int mi = 0; mi < 4; mi++)
#pragma unroll
            for (int ni = 0; ni < 4; ni++)
                acc[mi][ni] = __builtin_amdgcn_mfma_f32_16x16x32_bf16(af[mi], bq[ni], acc[mi][ni], 0, 0, 0);
        __syncthreads();
    }
#pragma unroll
    for (int mi = 0; mi < 4; mi++) {
#pragma unroll
        for (int r = 0; r < 4; r++) {
            int row = m0 + wm + mi * 16 + quad * 4 + r;
#pragma unroll
            for (int ni = 0; ni < 4; ni++) {
                int col = n0 + wn + ni * 16 + lm;
                float v = acc[mi][ni][r];
                if constexpr (EPI == 1) {
                    v += resf[(size_t)(row & 15) * Dc + col];
                    Cf[(size_t)row * N + col] = v;
                } else if constexpr (EPI == 2) {
                    v = 0.5f * v * (1.f + erff(v * 0.70710678118654752f));
                    Cb[(size_t)row * N + col] = f2bf(v);
                } else if constexpr (EPI == 3) {
                    v += resf[(size_t)row * N + col];
                    Cf[(size_t)row * N + col] = v;
                } else {
                    v = rs[row] * (v - mu[row] * uvec[col]) + tvec[col];
                    Cb[(size_t)row * N + col] = f2bf(v);
                }
            }
        }
    }
}

// ================= FALLBACK GEMM (round-2 proven): VGPR staging, fp32 variants =================
template <int EPI, bool BKXN, bool AF32>
__global__ __launch_bounds__(256) void gemm_k(
    const void* __restrict__ Av, const void* __restrict__ Bv,
    u16* __restrict__ Cb, float* __restrict__ Cf,
    int M, int N, int K,
    const float* __restrict__ mu, const float* __restrict__ rs,
    const float* __restrict__ uvec, const float* __restrict__ tvec,
    const float* __restrict__ resf) {
    __shared__ __align__(16) u16 As[128 * 32];
    __shared__ __align__(16) u16 Bs[128 * 32];
    int tid = threadIdx.x;
    unsigned l = blockIdx.y * gridDim.x + blockIdx.x;
    unsigned G = gridDim.x * gridDim.y;
    unsigned wl = (l & 7u) * (G >> 3) + (l >> 3);
    int nt = wl % gridDim.x, mt = wl / gridDim.x;
    int m0 = mt * 128, n0 = nt * 128;
    int lane = tid & 63, wave = tid >> 6;
    int wm = (wave & 1) << 6, wn = (wave >> 1) << 6;
    int lm = lane & 15, quad = lane >> 4;
    int ko = quad * 8;

    const float* Af = (const float*)Av;
    const u16* Ab = (const u16*)Av;
    const float* Bf = (const float*)Bv;
    const u16* Bb = (const u16*)Bv;

    f32x4 acc[4][4];
#pragma unroll
    for (int mi = 0; mi < 4; mi++)
#pragma unroll
        for (int ni = 0; ni < 4; ni++) acc[mi][ni] = f32x4{0.f, 0.f, 0.f, 0.f};

    for (int k0 = 0; k0 < K; k0 += 32) {
        if (AF32) {
#pragma unroll
            for (int it = 0; it < 4; ++it) {
                int cid = tid + (it << 8);
                int row = cid >> 3, qq = cid & 7;
                float4 f = *(const float4*)(Af + (size_t)(m0 + row) * K + k0 + qq * 4);
                uint2 pk;
                pk.x = pk2bf(f.x, f.y);
                pk.y = pk2bf(f.z, f.w);
                *(uint2*)&As[row * 32 + qq * 4] = pk;
            }
        } else {
#pragma unroll
            for (int it = 0; it < 2; ++it) {
                int cid = tid + (it << 8);
                int row = cid >> 2, cc = cid & 3;
                *(uint4*)&As[row * 32 + cc * 8] = *(const uint4*)(Ab + (size_t)(m0 + row) * K + k0 + cc * 8);
            }
        }
        if (!BKXN) {
#pragma unroll
            for (int it = 0; it < 2; ++it) {
                int cid = tid + (it << 8);
                int row = cid >> 2, cc = cid & 3;
                *(uint4*)&Bs[row * 32 + cc * 8] = *(const uint4*)(Bb + (size_t)(n0 + row) * K + k0 + cc * 8);
            }
        } else {
#pragma unroll
            for (int it = 0; it < 4; ++it) {
                int cid = tid + (it << 8);
                int kk = cid >> 5, nc = cid & 31;
                float4 f = *(const float4*)(Bf + (size_t)(k0 + kk) * N + n0 + nc * 4);
                Bs[(nc * 4 + 0) * 32 + kk] = f2bf(f.x);
                Bs[(nc * 4 + 1) * 32 + kk] = f2bf(f.y);
                Bs[(nc * 4 + 2) * 32 + kk] = f2bf(f.z);
                Bs[(nc * 4 + 3) * 32 + kk] = f2bf(f.w);
            }
        }
        __syncthreads();
        bf16x8 af[4], bq[4];
#pragma unroll
        for (int mi = 0; mi < 4; mi++) af[mi] = *(const bf16x8*)&As[(wm + mi * 16 + lm) * 32 + ko];
#pragma unroll
        for (int ni = 0; ni < 4; ni++) bq[ni] = *(const bf16x8*)&Bs[(wn + ni * 16 + lm) * 32 + ko];
#pragma unroll
        for (int mi = 0; mi < 4; mi++)
#pragma unroll
            for (int ni = 0; ni < 4; ni++)
                acc[mi][ni] = __builtin_amdgcn_mfma_f32_16x16x32_bf16(af[mi], bq[ni], acc[mi][ni], 0, 0, 0);
        __syncthreads();
    }
#pragma unroll
    for (int mi = 0; mi < 4; mi++) {
#pragma unroll
        for (int r = 0; r < 4; r++) {
            int row = m0 + wm + mi * 16 + quad * 4 + r;
#pragma unroll
            for (int ni = 0; ni < 4; ni++) {
                int col = n0 + wn + ni * 16 + lm;
                float v = acc[mi][ni][r];
                if constexpr (EPI == 1) {
                    v += resf[(size_t)(row & 15) * Dc + col];
                    Cf[(size_t)row * N + col] = v;
                } else if constexpr (EPI == 2) {
                    v = 0.5f * v * (1.f + erff(v * 0.70710678118654752f));
                    Cb[(size_t)row * N + col] = f2bf(v);
                } else if constexpr (EPI == 3) {
                    v += resf[(size_t)row * N + col];
                    Cf[(size_t)row * N + col] = v;
                } else {
                    v = rs[row] * (v - mu[row] * uvec[col]) + tvec[col];
                    Cb[(size_t)row * N + col] = f2bf(v);
                }
            }
        }
    }
}

// ---- sim[bth][i][j] = q . k  (q fp32, k bf16) ----
__global__ __launch_bounds__(256) void sim_qk_k(const float* __restrict__ q, const u16* __restrict__ kv,
                                                float* __restrict__ sim) {
    __shared__ float qs[16 * 96];
    __shared__ __align__(16) u16 ks[256 * 96];
    int bth = blockIdx.x, bt = bth >> 3, h = bth & 7;
    int j0 = blockIdx.y * 256;
    for (int idx = threadIdx.x; idx < 1536; idx += 256) {
        int i = idx / 96, d = idx - i * 96;
        qs[idx] = q[i * INNERc + h * DHc + d];
    }
#pragma unroll
    for (int it = 0; it < 12; ++it) {
        int cid = threadIdx.x + it * 256;
        int row = cid / 12, c = cid - row * 12;
        *(uint4*)&ks[row * 96 + c * 8] =
            *(const uint4*)(kv + (size_t)(bt * Nc + j0 + row) * 1536 + h * DHc + c * 8);
    }
    __syncthreads();
    float acc[16];
#pragma unroll
    for (int i = 0; i < 16; i++) acc[i] = 0.f;
    int j = threadIdx.x;
#pragma unroll
    for (int c = 0; c < 12; c++) {
        uint4 raw = *(const uint4*)&ks[j * 96 + c * 8];
        const u16* pe = (const u16*)&raw;
        float kf[8];
#pragma unroll
        for (int e = 0; e < 8; e++) kf[e] = bf2f(pe[e]);
#pragma unroll
        for (int i = 0; i < 16; i++) {
            float a = 0.f;
#pragma unroll
            for (int e = 0; e < 8; e++) a += qs[i * 96 + c * 8 + e] * kf[e];
            acc[i] += a;
        }
    }
#pragma unroll
    for (int i = 0; i < 16; i++)
        sim[((size_t)bth * 16 + i) * Nc + j0 + j] = acc[i];
}

// ---- softmax row transform, exactly in reference order ----
__global__ __launch_bounds__(256) void softmax_k(float* __restrict__ sim, const int* __restrict__ mask,
                                                 const float* __restrict__ guid) {
    __shared__ float red[4];
    int r = blockIdx.x;
    int bt = r >> 7;
    float* row = sim + (size_t)r * Nc;
    const int* mrow = mask + bt * Nc;
    const float* grow = guid + bt * Nc;
    float v[7];
    float mx = FMINc;
#pragma unroll
    for (int e = 0; e < 7; e++) { v[e] = row[threadIdx.x + e * 256]; mx = fmaxf(mx, v[e]); }
    float max1 = block_max(mx, red);
    float mx2 = FMINc;
#pragma unroll
    for (int e = 0; e < 7; e++) {
        int j = threadIdx.x + e * 256;
        float s = v[e] - max1;
        if (mrow[j] != 0) s = FMINc;
        s *= grow[j];
        v[e] = s;
        mx2 = fmaxf(mx2, s);
    }
    float max2 = block_max(mx2, red);
    float sum = 0.f;
#pragma unroll
    for (int e = 0; e < 7; e++) { v[e] = expf(v[e] - max2); sum += v[e]; }
    float tot = block_sum(sum, red);
    float inv = 1.f / tot;
#pragma unroll
    for (int e = 0; e < 7; e++) row[threadIdx.x + e * 256] = v[e] * inv;
}

// ---- out[bt*16+i, h*96+d] = sum_j p[i][j] v[j][d] -> bf16 ----
__global__ __launch_bounds__(256) void attn_out_k(const float* __restrict__ sim, const u16* __restrict__ kv,
                                                  u16* __restrict__ aout) {
    __shared__ __align__(16) u16 vs[128 * 96];
    __shared__ float ps[16 * 128];
    int bth = blockIdx.x, bt = bth >> 3, h = bth & 7;
    float acc[6];
    int ie[6], de[6];
#pragma unroll
    for (int e = 0; e < 6; e++) {
        int el = threadIdx.x + e * 256;
        ie[e] = el / 96;
        de[e] = el - ie[e] * 96;
        acc[e] = 0.f;
    }
    for (int jt = 0; jt < 14; ++jt) {
        int j0 = jt * 128;
#pragma unroll
        for (int it = 0; it < 6; ++it) {
            int cid = threadIdx.x + it * 256;
            int row = cid / 12, c = cid - row * 12;
            *(uint4*)&vs[row * 96 + c * 8] =
                *(const uint4*)(kv + (size_t)(bt * Nc + j0 + row) * 1536 + INNERc + h * DHc + c * 8);
        }
#pragma unroll
        for (int it = 0; it < 8; ++it) {
            int cid = threadIdx.x + it * 256;
            int ii = cid >> 7, jj = cid & 127;
            ps[ii * 128 + jj] = sim[((size_t)bth * 16 + ii) * Nc + j0 + jj];
        }
        __syncthreads();
        for (int jj = 0; jj < 128; ++jj) {
#pragma unroll
            for (int e = 0; e < 6; e++)
                acc[e] += ps[ie[e] * 128 + jj] * bf2f(vs[jj * 96 + de[e]]);
        }
        __syncthreads();
    }
#pragma unroll
    for (int e = 0; e < 6; e++)
        aout[(size_t)(bt * 16 + ie[e]) * INNERc + h * DHc + de[e]] = f2bf(acc[e]);
}

// ---- LayerNorm over fp32 rows -> bf16 (OUTF32=false) or fp32 (true) ----
template <bool OUTF32>
__global__ __launch_bounds__(256) void ln_rows_k(const float* __restrict__ in, const float* __restrict__ g,
                                                 const float* __restrict__ b, void* __restrict__ outv) {
    __shared__ float red[4];
    int r = blockIdx.x;
    const float* row = in + (size_t)r * Dc;
    float4 v[4];
    float s = 0.f, s2 = 0.f;
#pragma unroll
    for (int it = 0; it < 4; ++it) {
        v[it] = *(const float4*)(row + (threadIdx.x + it * 256) * 4);
        s += v[it].x + v[it].y + v[it].z + v[it].w;
        s2 += v[it].x * v[it].x + v[it].y * v[it].y + v[it].z * v[it].z + v[it].w * v[it].w;
    }
    s = block_sum(s, red);
    s2 = block_sum(s2, red);
    float m = s * (1.f / Dc), rr = rsqrtf(s2 * (1.f / Dc) - m * m + EPSc);
#pragma unroll
    for (int it = 0; it < 4; ++it) {
        int base = (threadIdx.x + it * 256) * 4;
        float4 gg = *(const float4*)(g + base);
        float4 bb = *(const float4*)(b + base);
        float xs[4] = {v[it].x, v[it].y, v[it].z, v[it].w};
        float gs[4] = {gg.x, gg.y, gg.z, gg.w};
        float bs[4] = {bb.x, bb.y, bb.z, bb.w};
        float o[4];
#pragma unroll
        for (int e = 0; e < 4; e++) o[e] = (xs[e] - m) * rr * gs[e] + bs[e];
        if (OUTF32) {
            *(float4*)((float*)outv + (size_t)r * Dc + base) = make_float4(o[0], o[1], o[2], o[3]);
        } else {
            u16 tmp[4];
#pragma unroll
            for (int e = 0; e < 4; e++) tmp[e] = f2bf(o[e]);
            *(uint2*)((u16*)outv + (size_t)r * Dc + base) = *(uint2*)tmp;
        }
    }
}

extern "C" void kernel_launch(void* const* d_in, const int* in_sizes, int n_in,
                              void* d_out, int out_size, void* d_ws, size_t ws_size,
                              hipStream_t stream) {
    const float* x    = (const float*)d_in[0];
    const float* guid = (const float*)d_in[1];
    const int*   mask = (const int*)d_in[2];
    const float* lat  = (const float*)d_in[3];
    const float* nm_g = (const float*)d_in[4];
    const float* nm_b = (const float*)d_in[5];
    const float* nl_g = (const float*)d_in[6];
    const float* nl_b = (const float*)d_in[7];
    const float* wq   = (const float*)d_in[8];
    const float* wkv  = (const float*)d_in[9];
    const float* wout = (const float*)d_in[10];
    const float* ff_g = (const float*)d_in[11];
    const float* ff_b = (const float*)d_in[12];
    const float* w1   = (const float*)d_in[13];
    const float* w2   = (const float*)d_in[14];
    const float* fn_g = (const float*)d_in[15];
    const float* fn_b = (const float*)d_in[16];

    char* base = (char*)d_ws;
    size_t off = 0;
    auto alloc = [&](size_t bytes) -> void* {
        void* r = base + off;
        off = (off + bytes + 255) & ~(size_t)255;
        return r;
    };
    // common (~137 MB)
    u16*   kv    = (u16*)alloc((size_t)ROWS_X * 1536 * 2);
    u16*   wkvT  = (u16*)alloc((size_t)1536 * 4096 * 2);
    u16*   woutT = (u16*)alloc((size_t)4096 * 768 * 2);
    float* mu    = (float*)alloc((size_t)ROWS_X * 4);
    float* rs    = (float*)alloc((size_t)ROWS_X * 4);
    float* uvec  = (float*)alloc(1536 * 4);
    float* tvec  = (float*)alloc(1536 * 4);
    float* qb    = (float*)alloc((size_t)NLc * INNERc * 4);
    float* simb  = (float*)alloc((size_t)BTc * Hc * NLc * Nc * 4);
    u16*   aout  = (u16*)alloc((size_t)ROWS_L * INNERc * 2);
    float* lat1  = (float*)alloc((size_t)ROWS_L * Dc * 4);
    u16*   aff   = (u16*)alloc((size_t)ROWS_L * Dc * 2);
    u16*   hb    = (u16*)alloc((size_t)ROWS_L * FFc * 2);
    float* lat2  = (float*)alloc((size_t)ROWS_L * Dc * 4);
    // optional fast-path buffers (~369 MB more)
    size_t need_fast = off + (size_t)ROWS_X * Dc * 2 + (size_t)FFc * Dc * 2 * 2 + 4096;
    bool fast = ws_size >= need_fast;
    u16 *xb = nullptr, *w1T = nullptr, *w2T = nullptr;
    if (fast) {
        xb  = (u16*)alloc((size_t)ROWS_X * Dc * 2);
        w1T = (u16*)alloc((size_t)FFc * Dc * 2);
        w2T = (u16*)alloc((size_t)Dc * FFc * 2);
    }
    (void)in_sizes; (void)n_in; (void)out_size;

    // LN-fold vectors for the KV projection (parallelized: 192 blocks, atomic accumulate)
    zero_k<<<6, 256, 0, stream>>>(uvec, 1536);
    zero_k<<<6, 256, 0, stream>>>(tvec, 1536);
    colsums_part_k<<<dim3(6, 32), 256, 0, stream>>>(wkv, nm_g, nm_b, uvec, tvec, 1536);

    transpose_k<true><<<dim3(1536 / 32, 4096 / 32), 256, 0, stream>>>(wkv, wkvT, 4096, 1536, nm_g);
    transpose_k<false><<<dim3(4096 / 32, 768 / 32), 256, 0, stream>>>(wout, woutT, 768, 4096, nullptr);
    qproj_k<<<dim3(16, 3), 256, 0, stream>>>(lat, nl_g, nl_b, wq, qb);

    if (fast) {
        row_stats_k<true><<<ROWS_X, 256, 0, stream>>>(x, mu, rs, xb);
        transpose_k<false><<<dim3(FFc / 32, Dc / 32), 256, 0, stream>>>(w1, w1T, Dc, FFc, nullptr);
        transpose_k<false><<<dim3(Dc / 32, FFc / 32), 256, 0, stream>>>(w2, w2T, FFc, Dc, nullptr);

        gemm_bf_k<4><<<dim3(12, 224), 256, 0, stream>>>(xb, wkvT, kv, nullptr, ROWS_X, 1536, 4096,
                                                        mu, rs, uvec, tvec, nullptr);
        sim_qk_k<<<dim3(128, 7), 256, 0, stream>>>(qb, kv, simb);
        softmax_k<<<2048, 256, 0, stream>>>(simb, mask, guid);
        attn_out_k<<<128, 256, 0, stream>>>(simb, kv, aout);

        gemm_bf_k<1><<<dim3(32, 2), 256, 0, stream>>>(aout, woutT, nullptr, lat1, ROWS_L, 4096, 768,
                                                      nullptr, nullptr, nullptr, nullptr, lat);
        ln_rows_k<false><<<ROWS_L, 256, 0, stream>>>(lat1, ff_g, ff_b, aff);
        gemm_bf_k<2><<<dim3(64, 2), 256, 0, stream>>>(aff, w1T, hb, nullptr, ROWS_L, FFc, Dc,
                                                      nullptr, nullptr, nullptr, nullptr, nullptr);
        gemm_bf_k<3><<<dim3(32, 2), 256, 0, stream>>>(hb, w2T, nullptr, lat2, ROWS_L, Dc, FFc,
                                                      nullptr, nullptr, nullptr, nullptr, lat1);
    } else {
        row_stats_k<false><<<ROWS_X, 256, 0, stream>>>(x, mu, rs, nullptr);
        gemm_k<4, false, true><<<dim3(12, 224), 256, 0, stream>>>(x, wkvT, kv, nullptr, ROWS_X, 1536, 4096,
                                                                  mu, rs, uvec, tvec, nullptr);
        sim_qk_k<<<dim3(128, 7), 256, 0, stream>>>(qb, kv, simb);
        softmax_k<<<2048, 256, 0, stream>>>(simb, mask, guid);
        attn_out_k<<<128, 256, 0, stream>>>(simb, kv, aout);

        gemm_k<1, false, false><<<dim3(32, 2), 256, 0, stream>>>(aout, woutT, nullptr, lat1, ROWS_L, 4096, 768,
                                                                 nullptr, nullptr, nullptr, nullptr, lat);
        ln_rows_k<false><<<ROWS_L, 256, 0, stream>>>(lat1, ff_g, ff_b, aff);
        gemm_k<2, true, false><<<dim3(64, 2), 256, 0, stream>>>(aff, w1, hb, nullptr, ROWS_L, FFc, Dc,
                                                                nullptr, nullptr, nullptr, nullptr, nullptr);
        gemm_k<3, true, false><<<dim3(32, 2), 256, 0, stream>>>(hb, w2, nullptr, lat2, ROWS_L, Dc, FFc,
                                                                nullptr, nullptr, nullptr, nullptr, lat1);
    }
    ln_rows_k<true><<<ROWS_L, 256, 0, stream>>>(lat2, fn_g, fn_b, d_out);
}